// Round 1
// 263.632 us; speedup vs baseline: 1.0074x; 1.0074x over previous
//
#include <hip/hip_runtime.h>
#include <math.h>

// Fixed shape: N=8192 rows, D=4096 cols, fp32 in, fp32 scalar out.
#define N_ROWS 8192
#define D_COLS 4096
#define MARGIN 5.0f
#define PAIR_BLOCKS 256

typedef float v4f __attribute__((ext_vector_type(4)));

// ---------------------------------------------------------------------------
// dist: one WAVE per row, 4 rows per 256-block, grid 2048.
// R6 structure (best of prior session's R3-R6 sweep): stage the ENTIRE a-row
// in registers (16 float4/lane = 64 VGPRs), then stream the b-row with FMAs.
// The dataflow dependency forces all 16 a-loads live at once, giving a
// guaranteed 16-deep load batch and two MONOTONE 16 KB streams per wave.
// All loads nontemporal. UNCHANGED this round: variant sweep showed it is at
// its stream ceiling; this round attacks pair/final latency chains instead.
// dp[i] = (t==1) ? d : -inf ; dn[i] = (t==0) ? d : +inf  (self-masking hinge).
__global__ __launch_bounds__(256) void dist_kernel(
    const float* __restrict__ rx, const float* __restrict__ x,
    const int* __restrict__ tgt, float* __restrict__ dp, float* __restrict__ dn) {
  const int lane = threadIdx.x & 63;
  const int row  = blockIdx.x * 4 + (threadIdx.x >> 6);
  const v4f* a = reinterpret_cast<const v4f*>(rx) + (size_t)row * (D_COLS / 4);
  const v4f* b = reinterpret_cast<const v4f*>(x)  + (size_t)row * (D_COLS / 4);

  v4f ra[16];                                   // whole a-row: 64 VGPRs/lane
#pragma unroll
  for (int k = 0; k < 16; ++k) ra[k] = __builtin_nontemporal_load(&a[lane + k * 64]);

  float s0 = 0.f, s1 = 0.f, s2 = 0.f, s3 = 0.f;
#pragma unroll
  for (int k = 0; k < 16; ++k) {                // monotone b-stream + FMA
    v4f vb = __builtin_nontemporal_load(&b[lane + k * 64]);
    float d0 = ra[k].x - vb.x, d1 = ra[k].y - vb.y;
    float d2 = ra[k].z - vb.z, d3 = ra[k].w - vb.w;
    s0 = fmaf(d0, d0, s0); s1 = fmaf(d1, d1, s1);
    s2 = fmaf(d2, d2, s2); s3 = fmaf(d3, d3, s3);
  }
  float s = (s0 + s1) + (s2 + s3);
#pragma unroll
  for (int off = 32; off; off >>= 1) s += __shfl_down(s, off, 64);  // wave=64
  if (lane == 0) {
    float dd = sqrtf(s) + 0.001f;
    int t = tgt[row];
    dp[row] = (t == 1) ? dd : -INFINITY;
    dn[row] = (t == 0) ? dd : INFINITY;
  }
}

// ---------------------------------------------------------------------------
// pairs: NO atomics, NO fences. 256 blocks; each thread caches 32 dn values in
// registers; block strides over i (32 rows each); one f32 partial per block.
// R7: (a) preload ALL 32 dp values up-front (32 independent loads, one
// round-trip) instead of a 32-deep serial load->branch chain (~5 us of pure
// L2/L3 latency); j-loop FULLY unrolled so dpv[] stays in registers (rule:
// runtime-indexed reg arrays spill to scratch). (b) count positives here
// (each block visits a disjoint 1/256 of rows) so final_kernel need not
// re-read all 8192 dp. The +-inf encoding zeroes masked pairs (no NaN
// possible: only -inf-(+inf)).
__global__ __launch_bounds__(256) void pair_kernel(
    const float* __restrict__ dp, const float* __restrict__ dn,
    float* __restrict__ partial, int* __restrict__ pcount) {
  float r[N_ROWS / 256];
#pragma unroll
  for (int k = 0; k < N_ROWS / 256; ++k) r[k] = dn[threadIdx.x + k * 256];

  float dpv[N_ROWS / PAIR_BLOCKS];
#pragma unroll
  for (int j = 0; j < N_ROWS / PAIR_BLOCKS; ++j)
    dpv[j] = dp[blockIdx.x + j * PAIR_BLOCKS];

  float acc = 0.f;
  int pc = 0;                       // uniform across block; thread 0 writes it
#pragma unroll
  for (int j = 0; j < N_ROWS / PAIR_BLOCKS; ++j) {
    float dpi = dpv[j];
    if (dpi == -INFINITY) continue; // wave-uniform skip of non-pos rows
    ++pc;
    float dpi5 = dpi + MARGIN;
#pragma unroll
    for (int k = 0; k < N_ROWS / 256; ++k) acc += fmaxf(dpi5 - r[k], 0.f);
  }
#pragma unroll
  for (int off = 32; off; off >>= 1) acc += __shfl_down(acc, off, 64);
  __shared__ float ws[4];
  const int lane = threadIdx.x & 63, wid = threadIdx.x >> 6;
  if (lane == 0) ws[wid] = acc;
  __syncthreads();
  if (threadIdx.x == 0) {
    partial[blockIdx.x] = ws[0] + ws[1] + ws[2] + ws[3];
    pcount[blockIdx.x] = pc;
  }
}

// ---------------------------------------------------------------------------
// finalize: one block. Reduce 256 partials (in double) + 256 counts; write
// mean. R7: counts come from pair_kernel's pcount -- no 8192-elem dp re-read.
__global__ __launch_bounds__(256) void final_kernel(
    const float* __restrict__ partial, const int* __restrict__ pcount,
    float* __restrict__ out) {
  double s = (double)partial[threadIdx.x];
  int c = pcount[threadIdx.x];
#pragma unroll
  for (int off = 32; off; off >>= 1) {
    s += __shfl_down(s, off, 64);
    c += __shfl_down(c, off, 64);
  }
  __shared__ double sws[4];
  __shared__ int cws[4];
  const int lane = threadIdx.x & 63, wid = threadIdx.x >> 6;
  if (lane == 0) { sws[wid] = s; cws[wid] = c; }
  __syncthreads();
  if (threadIdx.x == 0) {
    double tot = sws[0] + sws[1] + sws[2] + sws[3];
    long long np = cws[0] + cws[1] + cws[2] + cws[3];
    long long cnt = np * (long long)(N_ROWS - np);
    out[0] = (float)(tot / (double)cnt);
  }
}

// ---------------------------------------------------------------------------
extern "C" void kernel_launch(void* const* d_in, const int* in_sizes, int n_in,
                              void* d_out, int out_size, void* d_ws, size_t ws_size,
                              hipStream_t stream) {
  const float* rx  = (const float*)d_in[0];
  const float* x   = (const float*)d_in[1];
  const int*   tgt = (const int*)d_in[2];
  float* out = (float*)d_out;

  // ws layout: dp[8192] f32 | dn[8192] f32 | partial[256] f32 | pcount[256] i32
  float* dp      = (float*)d_ws;
  float* dn      = dp + N_ROWS;
  float* partial = dn + N_ROWS;
  int*   pcount  = (int*)(partial + PAIR_BLOCKS);

  dist_kernel<<<N_ROWS / 4, 256, 0, stream>>>(rx, x, tgt, dp, dn);
  pair_kernel<<<PAIR_BLOCKS, 256, 0, stream>>>(dp, dn, partial, pcount);
  final_kernel<<<1, 256, 0, stream>>>(partial, pcount, out);
}